// Round 9
// baseline (110.701 us; speedup 1.0000x reference)
//
#include <hip/hip_runtime.h>
#include <hip/hip_fp16.h>

// Problem constants
constexpr int B_TOT = 8192;      // batch
constexpr int NM    = 64;        // n_models
constexpr int TT    = 16;        // trees per split
constexpr int LF    = 64;        // maxleaf
constexpr int EM    = 32;        // emb dim
constexpr int XROW  = NM * TT;   // 1024 ints per x row
constexpr int TROWS = TT * LF;   // 1024 rows per model table

// Broadcast quad-lane TQ's int4 to all 4 lanes of each quad via DPP
// (VALU pipe — does NOT load the LDS pipe like __shfl/ds_bpermute would).
template<int TQ>
__device__ __forceinline__ int4 qbcast(int4 v) {
    constexpr int c = TQ * 0x55;          // quad_perm [TQ,TQ,TQ,TQ]
    int4 r;
    r.x = __builtin_amdgcn_mov_dpp(v.x, c, 0xf, 0xf, true);
    r.y = __builtin_amdgcn_mov_dpp(v.y, c, 0xf, 0xf, true);
    r.z = __builtin_amdgcn_mov_dpp(v.z, c, 0xf, 0xf, true);
    r.w = __builtin_amdgcn_mov_dpp(v.w, c, 0xf, 0xf, true);
    return r;
}

__device__ __forceinline__ __half2 H2(unsigned u) { return *(const __half2*)&u; }

// ---------------------------------------------------------------------------
// K1: per-channel batch stats from an LDS-resident f16 table.
// (Note: the 64KB table CANNOT be split across blocks — sum-of-squares needs
// the full 16-t h per block — so 2 blocks/CU is structural.)
// New in R9: packs each (b,m)'s 16 indices into 16B (uint8 x16) and stores
// to x8 so k_out reads 8MB instead of 32MB. Stores are fire-and-forget,
// hidden under the LDS-gather-bound main loop.
// Block: 512 thr owns model m; 8 phases x 128 b; lane quad f owns t-quad f,
// indices broadcast within quad via v_mov_dpp. Partials per (chunk,m).
// ---------------------------------------------------------------------------
__global__ __launch_bounds__(512, 4) void k_stats_f16(
    const int* __restrict__ x, const float* __restrict__ tbl,
    float* __restrict__ psum, float* __restrict__ psq,
    unsigned* __restrict__ x8)
{
    __shared__ uint4 tb[TROWS * 4];      // 64KB f16 table: [row][quad of 8 ch]
    __shared__ float red[2][8][32];      // 2KB reduction scratch

    const int m     = blockIdx.x & 63;
    const int chunk = blockIdx.x >> 6;   // 0..7
    const int tid   = threadIdx.x;
    const int f     = tid & 3;           // channel quad (8 ch) AND t-quad owned
    const int grp   = tid >> 2;          // 0..127 = b within phase
    const int b0    = chunk * 1024;

    // ---- stage + convert table m: f32 128KB -> f16 64KB (4096 uint4) ----
    {
        const float4* __restrict__ src = (const float4*)(tbl + (size_t)m * (TROWS * EM));
#pragma unroll
        for (int i = 0; i < 8; ++i) {
            const int o = tid + i * 512;             // uint4 index 0..4095
            const float4 a = src[o * 2];
            const float4 c = src[o * 2 + 1];
            uint4 p;
            __half2 h0 = __floats2half2_rn(a.x, a.y);
            __half2 h1 = __floats2half2_rn(a.z, a.w);
            __half2 h2 = __floats2half2_rn(c.x, c.y);
            __half2 h3 = __floats2half2_rn(c.z, c.w);
            p.x = *(unsigned*)&h0; p.y = *(unsigned*)&h1;
            p.z = *(unsigned*)&h2; p.w = *(unsigned*)&h3;
            tb[o] = p;
        }
    }

    // ---- prefetch x for phase 0: ONE int4 per lane (t-quad f of b0+grp) ----
    int4 xr = ((const int4*)(x + (size_t)(b0 + grp) * XROW + m * TT))[f];

    float s[8], s2[8];
#pragma unroll
    for (int k = 0; k < 8; ++k) { s[k] = 0.f; s2[k] = 0.f; }

    __syncthreads();                     // tb ready

    for (int p = 0; p < 8; ++p) {
        const int b = b0 + p * 128 + grp;
        int4 nxt;
        if (p < 7)                       // next phase's x; hides behind gather
            nxt = ((const int4*)(x + (size_t)(b + 128) * XROW + m * TT))[f];

        // pack this lane's 4 indices (each <64) -> 1 dword of x8[b][m]
        x8[((size_t)b * NM + m) * 4 + f] =
            (unsigned)(xr.x & 0xff) | ((unsigned)(xr.y & 0xff) << 8) |
            ((unsigned)(xr.z & 0xff) << 16) | ((unsigned)xr.w << 24);

        // all 16 tree indices of this quad's b, via quad broadcast
        const int4 q0 = qbcast<0>(xr);
        const int4 q1 = qbcast<1>(xr);
        const int4 q2 = qbcast<2>(xr);
        const int4 q3 = qbcast<3>(xr);

        __half2 h0 = __half2(__half(0.f), __half(0.f));
        __half2 h1 = h0, h2 = h0, h3 = h0;

#define GATH(Q, RB)                                                          \
        {                                                                    \
            const uint4 a0 = tb[((Q).x + RB      ) * 4 + f];                 \
            const uint4 a1 = tb[((Q).y + RB +  64) * 4 + f];                 \
            const uint4 a2 = tb[((Q).z + RB + 128) * 4 + f];                 \
            const uint4 a3 = tb[((Q).w + RB + 192) * 4 + f];                 \
            h0 = __hadd2(h0, __hadd2(__hadd2(H2(a0.x), H2(a1.x)),            \
                                     __hadd2(H2(a2.x), H2(a3.x))));          \
            h1 = __hadd2(h1, __hadd2(__hadd2(H2(a0.y), H2(a1.y)),            \
                                     __hadd2(H2(a2.y), H2(a3.y))));          \
            h2 = __hadd2(h2, __hadd2(__hadd2(H2(a0.z), H2(a1.z)),            \
                                     __hadd2(H2(a2.z), H2(a3.z))));          \
            h3 = __hadd2(h3, __hadd2(__hadd2(H2(a0.w), H2(a1.w)),            \
                                     __hadd2(H2(a2.w), H2(a3.w))));          \
        }
        GATH(q0, 0) GATH(q1, 256) GATH(q2, 512) GATH(q3, 768)
#undef GATH

        const __half2 hv[4] = {h0, h1, h2, h3};
#pragma unroll
        for (int k = 0; k < 4; ++k) {
            const float lo = __low2float(hv[k]);
            const float hi = __high2float(hv[k]);
            s[2*k]   += lo;  s2[2*k]   = fmaf(lo, lo, s2[2*k]);
            s[2*k+1] += hi;  s2[2*k+1] = fmaf(hi, hi, s2[2*k+1]);
        }
        xr = nxt;
    }

    // ---- reduce over grp: butterfly within wave (grp bits = lane 2..5) ----
#pragma unroll
    for (int off = 4; off <= 32; off <<= 1) {
#pragma unroll
        for (int k = 0; k < 8; ++k) {
            s[k]  += __shfl_xor(s[k],  off);
            s2[k] += __shfl_xor(s2[k], off);
        }
    }
    const int wave = tid >> 6;
    if ((tid & 63) < 4) {
#pragma unroll
        for (int k = 0; k < 8; ++k) {
            red[0][wave][f * 8 + k] = s[k];
            red[1][wave][f * 8 + k] = s2[k];
        }
    }
    __syncthreads();
    if (tid < 32) {
        float a = 0.f, a2 = 0.f;
#pragma unroll
        for (int w = 0; w < 8; ++w) { a += red[0][w][tid]; a2 += red[1][w][tid]; }
        psum[(chunk * NM + m) * EM + tid] = a;   // per-(chunk,m) partials:
        psq [(chunk * NM + m) * EM + tid] = a2;  // no atomics, no memset
    }
}

// ---------------------------------------------------------------------------
// K2: sum the 8 chunk-partials, fold BN + projection:
//   a[m,e]=istd*gamma*w; C[m]=bout_b[m]+sum_e (beta-mean*istd*gamma)*w
//   g2[row*64+m] = dot(tbl[m,row,:], a[m,:])
// Grid: 256 blocks = 64 m x 4 row-quarters, 256 threads.
// ---------------------------------------------------------------------------
__global__ __launch_bounds__(256) void k_prep(
    const float* __restrict__ tbl,
    const float* __restrict__ gamma, const float* __restrict__ beta,
    const float* __restrict__ bw, const float* __restrict__ bb,
    const float* __restrict__ psum, const float* __restrict__ psq,
    float* __restrict__ Cm, float* __restrict__ g2)
{
    const int m    = blockIdx.x >> 2;
    const int part = blockIdx.x & 3;
    __shared__ float a_s[EM];
    if (threadIdx.x < EM) {
        const int e  = threadIdx.x;
        const int ch = m * EM + e;
        float sum = 0.f, sq = 0.f;
#pragma unroll
        for (int c = 0; c < 8; ++c) {
            sum += psum[(c * NM + m) * EM + e];
            sq  += psq [(c * NM + m) * EM + e];
        }
        const float inv_n = 1.f / (float)B_TOT;
        const float mean = sum * inv_n;
        const float var  = sq * inv_n - mean * mean;
        const float istd = rsqrtf(var + 1e-5f);
        const float g = gamma[ch];
        const float w = bw[ch];
        a_s[e] = istd * g * w;
        float ct = (beta[ch] - mean * istd * g) * w;
#pragma unroll
        for (int off = 16; off > 0; off >>= 1) ct += __shfl_down(ct, off, 32);
        if (e == 0 && part == 0) Cm[m] = bb[m] + ct;
    }
    __syncthreads();

    const float* __restrict__ tblm = tbl + (size_t)m * (TROWS * EM);
    const int row = part * 256 + threadIdx.x;
    const float4* rp = (const float4*)(tblm + row * EM);
    float acc = 0.f;
#pragma unroll
    for (int i = 0; i < 8; ++i) {
        const float4 v = rp[i];
        acc += v.x * a_s[i*4+0] + v.y * a_s[i*4+1]
             + v.z * a_s[i*4+2] + v.w * a_s[i*4+3];
    }
    g2[row * NM + m] = acc;
}

// ---------------------------------------------------------------------------
// K3: out[b,m] = C[m] + sum_t g2[(t*64 + idx)*64 + m]; plus row sum.
// Reads packed x8 (16B per (b,m), one int4 per lane -> 1KB/wave coalesced)
// instead of raw x: 8MB vs 32MB. 256 blocks x 32 b's halves slab staging
// traffic vs R8 (64MB total). 64KB slab x 4 phases, 2 b's per wave per phase.
// ---------------------------------------------------------------------------
__global__ __launch_bounds__(1024) void k_out(
    const uint4* __restrict__ x8, const float* __restrict__ g2,
    const float* __restrict__ Cm, float* __restrict__ out)
{
    __shared__ float slab[4 * LF * NM];      // 64KB
    const int tid  = threadIdx.x;
    const int wid  = tid >> 6;               // 0..15
    const int lane = tid & 63;               // = m
    const int bA   = blockIdx.x * 32 + wid;
    const int bB   = bA + 16;

    const uint4 pa = x8[(size_t)bA * NM + lane];
    const uint4 pb = x8[(size_t)bB * NM + lane];

    float accA = 0.f, accB = 0.f;
#pragma unroll
    for (int ph = 0; ph < 4; ++ph) {
        if (ph) __syncthreads();             // done reading previous slab
        const float4* src = (const float4*)(g2 + (size_t)ph * (4 * LF * NM));
        float4* dst = (float4*)slab;
#pragma unroll
        for (int j = 0; j < 4; ++j) dst[tid + j * 1024] = src[tid + j * 1024];
        __syncthreads();

        const unsigned wa = (ph == 0) ? pa.x : (ph == 1) ? pa.y : (ph == 2) ? pa.z : pa.w;
        const unsigned wb = (ph == 0) ? pb.x : (ph == 1) ? pb.y : (ph == 2) ? pb.z : pb.w;
#pragma unroll
        for (int k = 0; k < 4; ++k) {
            const int ia = (wa >> (k * 8)) & 0xff;
            const int ib = (wb >> (k * 8)) & 0xff;
            accA += slab[k * (LF * NM) + ia * NM + lane];
            accB += slab[k * (LF * NM) + ib * NM + lane];
        }
    }

    const float cm = Cm[lane];
    const float oA = accA + cm;
    const float oB = accB + cm;
    float sA = oA, sB = oB;
#pragma unroll
    for (int off = 32; off > 0; off >>= 1) {
        sA += __shfl_down(sA, off);
        sB += __shfl_down(sB, off);
    }
    out[B_TOT + (size_t)bA * NM + lane] = oA;
    out[B_TOT + (size_t)bB * NM + lane] = oB;
    if (lane == 0) { out[bA] = sA; out[bB] = sB; }
}

// ---------------------------------------------------------------------------
extern "C" void kernel_launch(void* const* d_in, const int* in_sizes, int n_in,
                              void* d_out, int out_size, void* d_ws, size_t ws_size,
                              hipStream_t stream) {
    const int*   x       = (const int*)d_in[0];
    const float* embed_w = (const float*)d_in[1];
    const float* gamma   = (const float*)d_in[2];
    const float* beta    = (const float*)d_in[3];
    const float* bout_w  = (const float*)d_in[4];
    const float* bout_b  = (const float*)d_in[5];
    float* out = (float*)d_out;

    float* ws   = (float*)d_ws;
    float* Cm   = ws;                 // 64
    float* g2   = ws + 64;            // 65536
    float* psum = ws + 64 + 65536;    // 16384
    float* psq  = psum + 16384;       // 16384
    unsigned* x8 = (unsigned*)(psq + 16384);   // 8192*64*4 dwords = 8MB

    k_stats_f16<<<dim3(512), dim3(512), 0, stream>>>(x, embed_w, psum, psq, x8);
    k_prep<<<dim3(256), dim3(256),  0, stream>>>(embed_w, gamma, beta, bout_w,
                                                 bout_b, psum, psq, Cm, g2);
    k_out <<<dim3(256), dim3(1024), 0, stream>>>((const uint4*)x8, g2, Cm, out);
}

// Round 11
// 108.819 us; speedup vs baseline: 1.0173x; 1.0173x over previous
//
#include <hip/hip_runtime.h>
#include <hip/hip_fp16.h>

// Problem constants
constexpr int B_TOT = 8192;      // batch
constexpr int NM    = 64;        // n_models
constexpr int TT    = 16;        // trees per split
constexpr int LF    = 64;        // maxleaf
constexpr int EM    = 32;        // emb dim
constexpr int XROW  = NM * TT;   // 1024 ints per x row
constexpr int TROWS = TT * LF;   // 1024 rows per model table

// Broadcast quad-lane TQ's int4 to all 4 lanes of each quad via DPP
// (VALU pipe — does NOT load the LDS pipe like __shfl/ds_bpermute would).
template<int TQ>
__device__ __forceinline__ int4 qbcast(int4 v) {
    constexpr int c = TQ * 0x55;          // quad_perm [TQ,TQ,TQ,TQ]
    int4 r;
    r.x = __builtin_amdgcn_mov_dpp(v.x, c, 0xf, 0xf, true);
    r.y = __builtin_amdgcn_mov_dpp(v.y, c, 0xf, 0xf, true);
    r.z = __builtin_amdgcn_mov_dpp(v.z, c, 0xf, 0xf, true);
    r.w = __builtin_amdgcn_mov_dpp(v.w, c, 0xf, 0xf, true);
    return r;
}

__device__ __forceinline__ __half2 H2(unsigned u) { return *(const __half2*)&u; }

// ---------------------------------------------------------------------------
// K1: per-channel batch stats from an LDS-resident f16 table.
// (Known-good R8 version: dpp in-quad broadcast, per-(chunk,m) partials,
//  no atomics/memset. R9's x8-pack stores here regressed — removed.)
// Block: 512 thr owns model m; 64KB f16 table in LDS; 8 phases x 128 b;
// lane quad f owns channel-quad f AND t-quad f.
// ---------------------------------------------------------------------------
__global__ __launch_bounds__(512, 4) void k_stats_f16(
    const int* __restrict__ x, const float* __restrict__ tbl,
    float* __restrict__ psum, float* __restrict__ psq)
{
    __shared__ uint4 tb[TROWS * 4];      // 64KB f16 table: [row][quad of 8 ch]
    __shared__ float red[2][8][32];      // 2KB reduction scratch

    const int m     = blockIdx.x & 63;
    const int chunk = blockIdx.x >> 6;   // 0..7
    const int tid   = threadIdx.x;
    const int f     = tid & 3;           // channel quad (8 ch) AND t-quad owned
    const int grp   = tid >> 2;          // 0..127 = b within phase
    const int b0    = chunk * 1024;

    // ---- stage + convert table m: f32 128KB -> f16 64KB (4096 uint4) ----
    {
        const float4* __restrict__ src = (const float4*)(tbl + (size_t)m * (TROWS * EM));
#pragma unroll
        for (int i = 0; i < 8; ++i) {
            const int o = tid + i * 512;             // uint4 index 0..4095
            const float4 a = src[o * 2];
            const float4 c = src[o * 2 + 1];
            uint4 p;
            __half2 h0 = __floats2half2_rn(a.x, a.y);
            __half2 h1 = __floats2half2_rn(a.z, a.w);
            __half2 h2 = __floats2half2_rn(c.x, c.y);
            __half2 h3 = __floats2half2_rn(c.z, c.w);
            p.x = *(unsigned*)&h0; p.y = *(unsigned*)&h1;
            p.z = *(unsigned*)&h2; p.w = *(unsigned*)&h3;
            tb[o] = p;
        }
    }

    // ---- prefetch x for phase 0: ONE int4 per lane (t-quad f of b0+grp) ----
    int4 xr = ((const int4*)(x + (size_t)(b0 + grp) * XROW + m * TT))[f];

    float s[8], s2[8];
#pragma unroll
    for (int k = 0; k < 8; ++k) { s[k] = 0.f; s2[k] = 0.f; }

    __syncthreads();                     // tb ready

    for (int p = 0; p < 8; ++p) {
        int4 nxt;
        if (p < 7)                       // next phase's x; hides behind gather
            nxt = ((const int4*)(x + (size_t)(b0 + (p + 1) * 128 + grp) * XROW + m * TT))[f];

        // all 16 tree indices of this quad's b, via quad broadcast
        const int4 q0 = qbcast<0>(xr);
        const int4 q1 = qbcast<1>(xr);
        const int4 q2 = qbcast<2>(xr);
        const int4 q3 = qbcast<3>(xr);

        __half2 h0 = __half2(__half(0.f), __half(0.f));
        __half2 h1 = h0, h2 = h0, h3 = h0;

#define GATH(Q, RB)                                                          \
        {                                                                    \
            const uint4 a0 = tb[((Q).x + RB      ) * 4 + f];                 \
            const uint4 a1 = tb[((Q).y + RB +  64) * 4 + f];                 \
            const uint4 a2 = tb[((Q).z + RB + 128) * 4 + f];                 \
            const uint4 a3 = tb[((Q).w + RB + 192) * 4 + f];                 \
            h0 = __hadd2(h0, __hadd2(__hadd2(H2(a0.x), H2(a1.x)),            \
                                     __hadd2(H2(a2.x), H2(a3.x))));          \
            h1 = __hadd2(h1, __hadd2(__hadd2(H2(a0.y), H2(a1.y)),            \
                                     __hadd2(H2(a2.y), H2(a3.y))));          \
            h2 = __hadd2(h2, __hadd2(__hadd2(H2(a0.z), H2(a1.z)),            \
                                     __hadd2(H2(a2.z), H2(a3.z))));          \
            h3 = __hadd2(h3, __hadd2(__hadd2(H2(a0.w), H2(a1.w)),            \
                                     __hadd2(H2(a2.w), H2(a3.w))));          \
        }
        GATH(q0, 0) GATH(q1, 256) GATH(q2, 512) GATH(q3, 768)
#undef GATH

        const __half2 hv[4] = {h0, h1, h2, h3};
#pragma unroll
        for (int k = 0; k < 4; ++k) {
            const float lo = __low2float(hv[k]);
            const float hi = __high2float(hv[k]);
            s[2*k]   += lo;  s2[2*k]   = fmaf(lo, lo, s2[2*k]);
            s[2*k+1] += hi;  s2[2*k+1] = fmaf(hi, hi, s2[2*k+1]);
        }
        xr = nxt;
    }

    // ---- reduce over grp: butterfly within wave (grp bits = lane 2..5) ----
#pragma unroll
    for (int off = 4; off <= 32; off <<= 1) {
#pragma unroll
        for (int k = 0; k < 8; ++k) {
            s[k]  += __shfl_xor(s[k],  off);
            s2[k] += __shfl_xor(s2[k], off);
        }
    }
    const int wave = tid >> 6;
    if ((tid & 63) < 4) {
#pragma unroll
        for (int k = 0; k < 8; ++k) {
            red[0][wave][f * 8 + k] = s[k];
            red[1][wave][f * 8 + k] = s2[k];
        }
    }
    __syncthreads();
    if (tid < 32) {
        float a = 0.f, a2 = 0.f;
#pragma unroll
        for (int w = 0; w < 8; ++w) { a += red[0][w][tid]; a2 += red[1][w][tid]; }
        psum[(chunk * NM + m) * EM + tid] = a;
        psq [(chunk * NM + m) * EM + tid] = a2;
    }
}

// ---------------------------------------------------------------------------
// K2: sum the 8 chunk-partials, fold BN + projection:
//   a[m,e]=istd*gamma*w; C[m]=bout_b[m]+sum_e (beta-mean*istd*gamma)*w
//   g2[row*64+m] = dot(tbl[m,row,:], a[m,:])
// Grid: 256 blocks = 64 m x 4 row-quarters, 256 threads.
// ---------------------------------------------------------------------------
__global__ __launch_bounds__(256) void k_prep(
    const float* __restrict__ tbl,
    const float* __restrict__ gamma, const float* __restrict__ beta,
    const float* __restrict__ bw, const float* __restrict__ bb,
    const float* __restrict__ psum, const float* __restrict__ psq,
    float* __restrict__ Cm, float* __restrict__ g2)
{
    const int m    = blockIdx.x >> 2;
    const int part = blockIdx.x & 3;
    __shared__ float a_s[EM];
    if (threadIdx.x < EM) {
        const int e  = threadIdx.x;
        const int ch = m * EM + e;
        float sum = 0.f, sq = 0.f;
#pragma unroll
        for (int c = 0; c < 8; ++c) {
            sum += psum[(c * NM + m) * EM + e];
            sq  += psq [(c * NM + m) * EM + e];
        }
        const float inv_n = 1.f / (float)B_TOT;
        const float mean = sum * inv_n;
        const float var  = sq * inv_n - mean * mean;
        const float istd = rsqrtf(var + 1e-5f);
        const float g = gamma[ch];
        const float w = bw[ch];
        a_s[e] = istd * g * w;
        float ct = (beta[ch] - mean * istd * g) * w;
#pragma unroll
        for (int off = 16; off > 0; off >>= 1) ct += __shfl_down(ct, off, 32);
        if (e == 0 && part == 0) Cm[m] = bb[m] + ct;
    }
    __syncthreads();

    const float* __restrict__ tblm = tbl + (size_t)m * (TROWS * EM);
    const int row = part * 256 + threadIdx.x;
    const float4* rp = (const float4*)(tblm + row * EM);
    float acc = 0.f;
#pragma unroll
    for (int i = 0; i < 8; ++i) {
        const float4 v = rp[i];
        acc += v.x * a_s[i*4+0] + v.y * a_s[i*4+1]
             + v.z * a_s[i*4+2] + v.w * a_s[i*4+3];
    }
    g2[row * NM + m] = acc;
}

// ---------------------------------------------------------------------------
// K3: out[b,m] = C[m] + sum_t g2[(t*64 + x[b,m*16+t])*64 + m]; plus row sum.
// R8's known-good structure (raw per-lane x reads — L1 hits after first
// line touch) but 256 blocks x 32 b's (2 b's per wave): halves g2 slab
// re-staging to 64MB total and halves barriers per b. 64KB slab x 4 phases.
// Slab gather bank = m&31 -> 2 lanes/bank = free.
// ---------------------------------------------------------------------------
__global__ __launch_bounds__(1024) void k_out(
    const int* __restrict__ x, const float* __restrict__ g2,
    const float* __restrict__ Cm, float* __restrict__ out)
{
    __shared__ float slab[4 * LF * NM];      // 64KB
    const int tid  = threadIdx.x;
    const int wid  = tid >> 6;               // 0..15
    const int lane = tid & 63;               // = m
    const int bA   = blockIdx.x * 32 + wid;
    const int bB   = bA + 16;

    const int4* xa = (const int4*)(x + (size_t)bA * XROW + lane * TT);
    const int4* xb = (const int4*)(x + (size_t)bB * XROW + lane * TT);
    const int4 a0 = xa[0], a1 = xa[1], a2 = xa[2], a3 = xa[3];
    const int4 b0 = xb[0], b1 = xb[1], b2 = xb[2], b3 = xb[3];
    const int ia[16] = {a0.x,a0.y,a0.z,a0.w, a1.x,a1.y,a1.z,a1.w,
                        a2.x,a2.y,a2.z,a2.w, a3.x,a3.y,a3.z,a3.w};
    const int ib[16] = {b0.x,b0.y,b0.z,b0.w, b1.x,b1.y,b1.z,b1.w,
                        b2.x,b2.y,b2.z,b2.w, b3.x,b3.y,b3.z,b3.w};

    float accA = 0.f, accB = 0.f;
#pragma unroll
    for (int ph = 0; ph < 4; ++ph) {
        if (ph) __syncthreads();             // done reading previous slab
        const float4* src = (const float4*)(g2 + (size_t)ph * (4 * LF * NM));
        float4* dst = (float4*)slab;
#pragma unroll
        for (int j = 0; j < 4; ++j) dst[tid + j * 1024] = src[tid + j * 1024];
        __syncthreads();
#pragma unroll
        for (int k = 0; k < 4; ++k) {
            accA += slab[k * (LF * NM) + ia[ph * 4 + k] * NM + lane];
            accB += slab[k * (LF * NM) + ib[ph * 4 + k] * NM + lane];
        }
    }

    const float cm = Cm[lane];
    const float oA = accA + cm;
    const float oB = accB + cm;
    float sA = oA, sB = oB;
#pragma unroll
    for (int off = 32; off > 0; off >>= 1) {
        sA += __shfl_down(sA, off);
        sB += __shfl_down(sB, off);
    }
    out[B_TOT + (size_t)bA * NM + lane] = oA;
    out[B_TOT + (size_t)bB * NM + lane] = oB;
    if (lane == 0) { out[bA] = sA; out[bB] = sB; }
}

// ---------------------------------------------------------------------------
extern "C" void kernel_launch(void* const* d_in, const int* in_sizes, int n_in,
                              void* d_out, int out_size, void* d_ws, size_t ws_size,
                              hipStream_t stream) {
    const int*   x       = (const int*)d_in[0];
    const float* embed_w = (const float*)d_in[1];
    const float* gamma   = (const float*)d_in[2];
    const float* beta    = (const float*)d_in[3];
    const float* bout_w  = (const float*)d_in[4];
    const float* bout_b  = (const float*)d_in[5];
    float* out = (float*)d_out;

    float* ws   = (float*)d_ws;
    float* Cm   = ws;                 // 64
    float* g2   = ws + 64;            // 65536
    float* psum = ws + 64 + 65536;    // 16384
    float* psq  = psum + 16384;       // 16384

    k_stats_f16<<<dim3(512), dim3(512), 0, stream>>>(x, embed_w, psum, psq);
    k_prep<<<dim3(256), dim3(256),  0, stream>>>(embed_w, gamma, beta, bout_w,
                                                 bout_b, psum, psq, Cm, g2);
    k_out <<<dim3(256), dim3(1024), 0, stream>>>(x, g2, Cm, out);
}